// Round 12
// baseline (208.065 us; speedup 1.0000x reference)
//
#include <hip/hip_runtime.h>

// RGCNBlock: y = rgcn2(gelu(bn2(rgcn1(gelu(bn1(x)))))) + x
// N=50000, K=16, F=128, f32 in/out. bf16 MFMA 16x16x32; b1 cancels in BN2.
// R12: regime = COMPULSORY per-XCD gather replication (~93MB = 8 x 11.6MB)
// served by L3 at ~1.8-1.9 TB/s; schedule-invariant (R2/R6/R7/R8/R11 all
// ~74us). Only byte levers remain: h2 stored as fp8 e4m3 (row = 128B = one
// line), decoded in-register before bf16 MFMA. rgcn1 stays bf16 (its error
// passes BN2's ~3.3x amplification; fp8 there would blow the 0.12 budget).

#define NN  50000
#define NB  500
#define NPB 100

typedef __bf16 v8bf __attribute__((ext_vector_type(8)));
typedef unsigned short u8s __attribute__((ext_vector_type(8)));
typedef float  v4f  __attribute__((ext_vector_type(4)));
typedef float  vf2  __attribute__((ext_vector_type(2)));

__device__ __forceinline__ unsigned short f2bf(float f) {
  unsigned int u = __builtin_bit_cast(unsigned int, f);
  u += 0x7FFFu + ((u >> 16) & 1u);          // RNE
  return (unsigned short)(u >> 16);
}
__device__ __forceinline__ float bf2f(unsigned short s) {
  unsigned int u = ((unsigned int)s) << 16;
  return __builtin_bit_cast(float, u);
}
__device__ __forceinline__ float gelu_f(float y) {
  return 0.5f * y * (1.0f + erff(y * 0.70710678118654752f));
}

// 8 packed fp8 (2 dwords) -> 8 bf16 (one MFMA A-fragment)
__device__ __forceinline__ v8bf fp8x8_to_bf16x8(unsigned int lo, unsigned int hi) {
  vf2 f0 = __builtin_amdgcn_cvt_pk_f32_fp8((int)lo, false);
  vf2 f1 = __builtin_amdgcn_cvt_pk_f32_fp8((int)lo, true);
  vf2 f2 = __builtin_amdgcn_cvt_pk_f32_fp8((int)hi, false);
  vf2 f3 = __builtin_amdgcn_cvt_pk_f32_fp8((int)hi, true);
  unsigned int d0, d1, d2, d3;
  asm("v_cvt_pk_bf16_f32 %0, %1, %2" : "=v"(d0) : "v"(f0.x), "v"(f0.y));
  asm("v_cvt_pk_bf16_f32 %0, %1, %2" : "=v"(d1) : "v"(f1.x), "v"(f1.y));
  asm("v_cvt_pk_bf16_f32 %0, %1, %2" : "=v"(d2) : "v"(f2.x), "v"(f2.y));
  asm("v_cvt_pk_bf16_f32 %0, %1, %2" : "=v"(d3) : "v"(f3.x), "v"(f3.y));
  uint4 u = make_uint4(d0, d1, d2, d3);
  return __builtin_bit_cast(v8bf, u);
}

// ---------------- W (F x K*F f32) -> bf16 in MFMA-B-fragment order ----------
__global__ void wconv_kernel(const float* __restrict__ W1, const float* __restrict__ W2,
                             unsigned short* __restrict__ Wt1, unsigned short* __restrict__ Wt2) {
  int t = blockIdx.x * 256 + threadIdx.x;            // 65536 total
  const float* W = (t >= 32768) ? W2 : W1;
  unsigned short* Wt = (t >= 32768) ? Wt2 : Wt1;
  int r = t & 32767;
  int frag = r >> 6, lane = r & 63;
  int k4 = frag >> 3, c = frag & 7;
  int o  = c * 16 + (lane & 15);
  int kd = k4 * 32 + (lane >> 4) * 8;
  const float* src = W + o * 2048 + kd;
  unsigned short* dst = Wt + r * 8;
#pragma unroll
  for (int j = 0; j < 8; ++j) dst[j] = f2bf(src[j]);
}

// ---------------- BN stats over x (f32), deterministic two-phase ------------
__global__ void bn_stats_kernel(const float* __restrict__ x, float* __restrict__ part) {
  float s0=0,s1=0,s2=0,s3=0,q0=0,q1=0,q2=0,q3=0;
  for (int cb = blockIdx.x; cb < (NN*128/1024); cb += 256) {
    float4 v = reinterpret_cast<const float4*>(x)[cb * 256 + threadIdx.x];
    s0+=v.x; q0+=v.x*v.x; s1+=v.y; q1+=v.y*v.y;
    s2+=v.z; q2+=v.z*v.z; s3+=v.w; q3+=v.w*v.w;
  }
  __shared__ float ls[1024], lsq[1024];
  int fb = (threadIdx.x & 31) * 4;
  int sl = threadIdx.x >> 5;
  ls[sl*128+fb]   = s0; ls[sl*128+fb+1]  = s1; ls[sl*128+fb+2]  = s2; ls[sl*128+fb+3]  = s3;
  lsq[sl*128+fb]  = q0; lsq[sl*128+fb+1] = q1; lsq[sl*128+fb+2] = q2; lsq[sl*128+fb+3] = q3;
  __syncthreads();
  if (threadIdx.x < 128) {
    float S=0,Q=0;
#pragma unroll
    for (int s2i=0; s2i<8; ++s2i){ S += ls[s2i*128+threadIdx.x]; Q += lsq[s2i*128+threadIdx.x]; }
    part[blockIdx.x*256 + threadIdx.x]       = S;
    part[blockIdx.x*256 + 128 + threadIdx.x] = Q;
  }
}

// ---------------- final reduce: 1 block x 1024 thr, 8 groups x 128 feats ----
__global__ __launch_bounds__(1024) void bn_reduce_kernel(
    const float* __restrict__ part, int nb,
    const float* __restrict__ gamma, const float* __restrict__ beta,
    float* __restrict__ scsh) {
  int f = threadIdx.x & 127;
  int g = threadIdx.x >> 7;
  float S = 0.f, Q = 0.f;
  for (int b = g; b < nb; b += 8) {
    S += part[b * 256 + f];
    Q += part[b * 256 + 128 + f];
  }
  __shared__ float ls[8][128], lq[8][128];
  ls[g][f] = S; lq[g][f] = Q;
  __syncthreads();
  if (threadIdx.x < 128) {
    float St = 0.f, Qt = 0.f;
#pragma unroll
    for (int i = 0; i < 8; ++i) { St += ls[i][f]; Qt += lq[i][f]; }
    float inv  = 1.0f / (float)NN;
    float mean = St * inv;
    float var  = fmaxf(Qt * inv - mean * mean, 0.0f);
    float sc   = gamma[f] * rsqrtf(var + 1e-5f);
    scsh[f]       = sc;
    scsh[128 + f] = beta[f] - mean * sc;
  }
}

// ---------------- apply BN + GELU (exact erf), f32 source -> bf16 -----------
__global__ void apply1_kernel(const float* __restrict__ x, const float* __restrict__ scsh,
                              unsigned short* __restrict__ h1) {
  int stride = gridDim.x * blockDim.x;
  for (int c = blockIdx.x * blockDim.x + threadIdx.x; c < NN*128/4; c += stride) {
    float4 v = reinterpret_cast<const float4*>(x)[c];
    int f = (c * 4) & 127;
    ushort4 o;
    o.x = f2bf(gelu_f(v.x * scsh[f]   + scsh[128+f]));
    o.y = f2bf(gelu_f(v.y * scsh[f+1] + scsh[128+f+1]));
    o.z = f2bf(gelu_f(v.z * scsh[f+2] + scsh[128+f+2]));
    o.w = f2bf(gelu_f(v.w * scsh[f+3] + scsh[128+f+3]));
    reinterpret_cast<ushort4*>(h1)[c] = o;
  }
}

// ---------------- apply BN + GELU, bf16 source -> fp8 e4m3 ------------------
__global__ void apply2_kernel(const unsigned short* __restrict__ t1,
                              const float* __restrict__ scsh,
                              unsigned int* __restrict__ h2) {
  int stride = gridDim.x * blockDim.x;
  for (int c = blockIdx.x * blockDim.x + threadIdx.x; c < NN*128/8; c += stride) {
    u8s v = reinterpret_cast<const u8s*>(t1)[c];      // 8 bf16
    int f = (c * 8) & 127;
    float r[8];
#pragma unroll
    for (int j = 0; j < 8; ++j)
      r[j] = gelu_f(bf2f((unsigned short)v[j]) * scsh[f + j] + scsh[128 + f + j]);
    int lo = __builtin_amdgcn_cvt_pk_fp8_f32(r[0], r[1], 0,  false);
    lo     = __builtin_amdgcn_cvt_pk_fp8_f32(r[2], r[3], lo, true);
    int hi = __builtin_amdgcn_cvt_pk_fp8_f32(r[4], r[5], 0,  false);
    hi     = __builtin_amdgcn_cvt_pk_fp8_f32(r[6], r[7], hi, true);
    reinterpret_cast<uint2*>(h2)[c] = make_uint2((unsigned)lo, (unsigned)hi);
  }
}

// ---------------- RGCN ------------------------------------------------------
// Block = 4 waves, exactly 100 nodes (500 blocks). B: single 32KB LDS tile
// via global_load_lds, R8 SLOT schedule. MODE 0 (rgcn1): A = bf16 rows of h1;
// epilogue = BN2 partials + LDS-transposed coalesced t1 store. MODE 1
// (rgcn2): A = fp8 rows of h2 (128B = 1 line), decoded in-register; epilogue
// = +b2 +x residual -> out f32.
template<int MODE>
__global__ __launch_bounds__(256, 2) void rgcn_kernel(
    const void* __restrict__ hb,
    const unsigned short* __restrict__ Wt,
    const int* __restrict__ graph,
    const float* __restrict__ bias,
    const float* __restrict__ xres,
    float* __restrict__ outf,
    unsigned short* __restrict__ outb,
    float* __restrict__ part)
{
  __shared__ unsigned short bsm[16384];      // 32KB: B tile, then t1 transpose
  __shared__ float lds_s[4][128];            // stats scratch (MODE 0)
  __shared__ float lds_q[4][128];

  const unsigned short* h16 = (const unsigned short*)hb;   // MODE 0
  const unsigned char*  h8  = (const unsigned char*)hb;    // MODE 1

  const int tid  = threadIdx.x;
  const int wv   = tid >> 6;
  const int lane = tid & 63;
  const int l15  = lane & 15;
  const int lq   = lane >> 4;
  const int nb0  = blockIdx.x * NPB;

  v4f acc[2][8];
#pragma unroll
  for (int rf = 0; rf < 2; ++rf)
#pragma unroll
    for (int c = 0; c < 8; ++c) acc[rf][c] = (v4f){0.f, 0.f, 0.f, 0.f};

  const int an0 = min(nb0 + wv * 32 + l15,      NN - 1);   // pad rows -> dup
  const int an1 = min(nb0 + wv * 32 + 16 + l15, NN - 1);

  // idx = row * 128 (elements; also bytes for fp8 since 1B/elem, rows 128B)
  int idx0[16], idx1[16];
  {
    const int4* g0 = reinterpret_cast<const int4*>(graph + an0 * 32);
    const int4* g1 = reinterpret_cast<const int4*>(graph + an1 * 32);
#pragma unroll
    for (int j = 0; j < 8; ++j) {
      int4 t0 = g0[j], t1v = g1[j];
      idx0[2*j]   = min(max(t0.y,  0), NN - 1) * 128;
      idx0[2*j+1] = min(max(t0.w,  0), NN - 1) * 128;
      idx1[2*j]   = min(max(t1v.y, 0), NN - 1) * 128;
      idx1[2*j+1] = min(max(t1v.w, 0), NN - 1) * 128;
    }
  }

  v8bf  A0[2][4],  A1[2][4];     // MODE 0 fragments (16B)
  uint2 A0q[2][4], A1q[2][4];    // MODE 1 fragments (8B fp8)

#define LOADA(buf_, s_) {                                                 \
    if constexpr (MODE == 0) {                                            \
      const unsigned short* r0 = h16 + idx0[s_] + lq * 8;                 \
      const unsigned short* r1 = h16 + idx1[s_] + lq * 8;                 \
      _Pragma("unroll")                                                   \
      for (int w4 = 0; w4 < 4; ++w4) {                                    \
        A0[buf_][w4] = *reinterpret_cast<const v8bf*>(r0 + w4 * 32);      \
        A1[buf_][w4] = *reinterpret_cast<const v8bf*>(r1 + w4 * 32);      \
      }                                                                   \
    } else {                                                              \
      const unsigned char* r0 = h8 + idx0[s_] + lq * 8;                   \
      const unsigned char* r1 = h8 + idx1[s_] + lq * 8;                   \
      _Pragma("unroll")                                                   \
      for (int w4 = 0; w4 < 4; ++w4) {                                    \
        A0q[buf_][w4] = *reinterpret_cast<const uint2*>(r0 + w4 * 32);    \
        A1q[buf_][w4] = *reinterpret_cast<const uint2*>(r1 + w4 * 32);    \
      }                                                                   \
    }                                                                     \
  }

#define STAGE(s_) {                                                           \
    const unsigned short* gsrc = Wt + (s_) * 16384 + wv * 4096 + lane * 8;    \
    unsigned short* ldst = &bsm[wv * 4096];                                   \
    _Pragma("unroll")                                                         \
    for (int i = 0; i < 8; ++i) {                                             \
      __builtin_amdgcn_global_load_lds(                                       \
        (const __attribute__((address_space(1))) void*)(gsrc + i * 512),      \
        (__attribute__((address_space(3))) void*)(ldst + i * 512),            \
        16, 0, 0);                                                            \
    }                                                                         \
  }

// index args masked so no OOB index appears textually (Sema array-bounds).
#define SLOT(s_) {                                                            \
    if ((s_) < 15) LOADA(((s_) + 1) & 1, ((s_) + 1) & 15)                     \
    __builtin_amdgcn_sched_barrier(0);                                        \
    __builtin_amdgcn_s_setprio(1);                                            \
    {                                                                         \
      const int cur_ = (s_) & 1;                                              \
      _Pragma("unroll")                                                       \
      for (int w4 = 0; w4 < 4; ++w4) {                                        \
        v8bf a0v, a1v;                                                        \
        if constexpr (MODE == 0) {                                            \
          a0v = A0[cur_][w4];                                                 \
          a1v = A1[cur_][w4];                                                 \
        } else {                                                              \
          a0v = fp8x8_to_bf16x8(A0q[cur_][w4].x, A0q[cur_][w4].y);            \
          a1v = fp8x8_to_bf16x8(A1q[cur_][w4].x, A1q[cur_][w4].y);            \
        }                                                                     \
        _Pragma("unroll")                                                     \
        for (int c = 0; c < 8; ++c) {                                         \
          v8bf b = *reinterpret_cast<const v8bf*>(                            \
              &bsm[(w4 * 8 + c) * 512 + lane * 8]);                           \
          acc[0][c] = __builtin_amdgcn_mfma_f32_16x16x32_bf16(                \
                        a0v, b, acc[0][c], 0, 0, 0);                          \
          acc[1][c] = __builtin_amdgcn_mfma_f32_16x16x32_bf16(                \
                        a1v, b, acc[1][c], 0, 0, 0);                          \
        }                                                                     \
      }                                                                       \
    }                                                                         \
    __builtin_amdgcn_s_setprio(0);                                            \
    __builtin_amdgcn_sched_barrier(0);                                        \
    __builtin_amdgcn_s_barrier();   /* all waves done reading bsm */          \
    __builtin_amdgcn_sched_barrier(0);                                        \
    if ((s_) < 15) STAGE(((s_) + 1) & 15)                                     \
    __syncthreads();                /* stage visible; gathers drained */      \
  }

  STAGE(0)
  LOADA(0, 0)
  __syncthreads();

  SLOT(0)  SLOT(1)  SLOT(2)  SLOT(3)
  SLOT(4)  SLOT(5)  SLOT(6)  SLOT(7)
  SLOT(8)  SLOT(9)  SLOT(10) SLOT(11)
  SLOT(12) SLOT(13) SLOT(14) SLOT(15)
#undef SLOT
#undef LOADA
#undef STAGE

  if constexpr (MODE == 0) {
    // BN2 partials (guarded to 100 valid rows) + bf16 into bsm tile,
    // then coalesced 16B/lane copy-out.
#pragma unroll
    for (int c = 0; c < 8; ++c) {
      float s = 0.f, q = 0.f;
#pragma unroll
      for (int rf = 0; rf < 2; ++rf) {
#pragma unroll
        for (int j = 0; j < 4; ++j) {
          int lrow = wv * 32 + rf * 16 + lq * 4 + j;    // C/D: row=(lane>>4)*4+reg
          float v  = acc[rf][c][j];
          if (lrow < NPB) { s += v; q += v * v; }
          bsm[lrow * 128 + c * 16 + l15] = f2bf(v);     // col = lane&15
        }
      }
      s += __shfl_xor(s, 16, 64); s += __shfl_xor(s, 32, 64);
      q += __shfl_xor(q, 16, 64); q += __shfl_xor(q, 32, 64);
      if (lq == 0) { lds_s[wv][c * 16 + l15] = s; lds_q[wv][c * 16 + l15] = q; }
    }
    __syncthreads();
    unsigned short* t1b = outb + nb0 * 128;
#pragma unroll
    for (int i = 0; i < 7; ++i) {
      int off = i * 2048 + tid * 8;                     // u16 units
      if (off < NPB * 128) {
        *reinterpret_cast<u8s*>(t1b + off) =
            *reinterpret_cast<const u8s*>(&bsm[off]);
      }
    }
    if (tid < 128) {
      float S = lds_s[0][tid] + lds_s[1][tid] + lds_s[2][tid] + lds_s[3][tid];
      float Q = lds_q[0][tid] + lds_q[1][tid] + lds_q[2][tid] + lds_q[3][tid];
      part[blockIdx.x * 256 + tid]       = S;
      part[blockIdx.x * 256 + 128 + tid] = Q;
    }
  } else {
#pragma unroll
    for (int c = 0; c < 8; ++c) {
      float bv = bias[c * 16 + l15];
#pragma unroll
      for (int rf = 0; rf < 2; ++rf) {
#pragma unroll
        for (int j = 0; j < 4; ++j) {
          int node = nb0 + wv * 32 + rf * 16 + lq * 4 + j;
          if (node < nb0 + NPB) {
            int idx = node * 128 + c * 16 + l15;
            outf[idx] = acc[rf][c][j] + bv + xres[idx];
          }
        }
      }
    }
  }
}

extern "C" void kernel_launch(void* const* d_in, const int* in_sizes, int n_in,
                              void* d_out, int out_size, void* d_ws, size_t ws_size,
                              hipStream_t stream) {
  const float* x      = (const float*)d_in[0];
  const int*   graph  = (const int*)d_in[1];
  const float* gamma1 = (const float*)d_in[2];
  const float* beta1  = (const float*)d_in[3];
  const float* W1     = (const float*)d_in[4];
  // d_in[5] = b1 : cancels inside BN2 (per-feature shift), skipped
  const float* gamma2 = (const float*)d_in[6];
  const float* beta2  = (const float*)d_in[7];
  const float* W2     = (const float*)d_in[8];
  const float* b2     = (const float*)d_in[9];
  float* out = (float*)d_out;

  char* ws = (char*)d_ws;
  // ws: h1(bf16)/h2(fp8) 12.8M | t1 12.8M | Wt1 512K | Wt2 512K | p1 | p2 | scsh
  unsigned short* h1  = (unsigned short*)(ws);
  unsigned short* t1  = (unsigned short*)(ws + 12800000);
  unsigned short* Wt1 = (unsigned short*)(ws + 25600000);
  unsigned short* Wt2 = (unsigned short*)(ws + 26124288);
  float* p1    = (float*)(ws + 26648576);
  float* p2    = (float*)(ws + 26910720);
  float* scsh1 = (float*)(ws + 27422720);
  float* scsh2 = (float*)(ws + 27423744);

  wconv_kernel<<<256, 256, 0, stream>>>(W1, W2, Wt1, Wt2);
  bn_stats_kernel<<<256, 256, 0, stream>>>(x, p1);
  bn_reduce_kernel<<<1, 1024, 0, stream>>>(p1, 256, gamma1, beta1, scsh1);
  apply1_kernel<<<2048, 256, 0, stream>>>(x, scsh1, h1);
  // args: (hb, Wt, graph, bias, xres, outf, outb, part)
  rgcn_kernel<0><<<NB, 256, 0, stream>>>(h1, Wt1, graph, nullptr, nullptr,
                                         nullptr, t1, p2);
  bn_reduce_kernel<<<1, 1024, 0, stream>>>(p2, NB, gamma2, beta2, scsh2);
  apply2_kernel<<<2048, 256, 0, stream>>>(t1, scsh2, (unsigned int*)h1);  // h2 (fp8) reuses h1
  rgcn_kernel<1><<<NB, 256, 0, stream>>>(h1, Wt2, graph, b2, x,
                                         out, nullptr, nullptr);
}

// Round 13
// 201.308 us; speedup vs baseline: 1.0336x; 1.0336x over previous
//
#include <hip/hip_runtime.h>

// RGCNBlock: y = rgcn2(gelu(bn2(rgcn1(gelu(bn1(x)))))) + x
// N=50000, K=16, F=128, f32 in/out. bf16 MFMA 16x16x32; b1 cancels in BN2.
// R13: R12 showed bytes DON'T matter (FETCH 113->51MB, dur const) -> wall is
// gather ADDRESS throughput (TA ~4 addr/cy/CU). Lever: fp8 row = 128B lets
// 2x dwordx4 (4 lanes x 16B) cover a row -> 4 gather instr/slot/wave vs 8.
// A-fragment k-mismatch fixed by permuting k in Wt2's swizzle (einsum is
// invariant to shared k-permutation). MODE 0 (bf16) already at instr floor.

#define NN  50000
#define NB  500
#define NPB 100

typedef __bf16 v8bf __attribute__((ext_vector_type(8)));
typedef unsigned short u8s __attribute__((ext_vector_type(8)));
typedef float  v4f  __attribute__((ext_vector_type(4)));
typedef float  vf2  __attribute__((ext_vector_type(2)));

__device__ __forceinline__ unsigned short f2bf(float f) {
  unsigned int u = __builtin_bit_cast(unsigned int, f);
  u += 0x7FFFu + ((u >> 16) & 1u);          // RNE
  return (unsigned short)(u >> 16);
}
__device__ __forceinline__ float bf2f(unsigned short s) {
  unsigned int u = ((unsigned int)s) << 16;
  return __builtin_bit_cast(float, u);
}
__device__ __forceinline__ float gelu_f(float y) {
  return 0.5f * y * (1.0f + erff(y * 0.70710678118654752f));
}

// 8 packed fp8 (2 dwords) -> 8 bf16 (one MFMA A-fragment)
__device__ __forceinline__ v8bf fp8x8_to_bf16x8(unsigned int lo, unsigned int hi) {
  vf2 f0 = __builtin_amdgcn_cvt_pk_f32_fp8((int)lo, false);
  vf2 f1 = __builtin_amdgcn_cvt_pk_f32_fp8((int)lo, true);
  vf2 f2 = __builtin_amdgcn_cvt_pk_f32_fp8((int)hi, false);
  vf2 f3 = __builtin_amdgcn_cvt_pk_f32_fp8((int)hi, true);
  unsigned int d0, d1, d2, d3;
  asm("v_cvt_pk_bf16_f32 %0, %1, %2" : "=v"(d0) : "v"(f0.x), "v"(f0.y));
  asm("v_cvt_pk_bf16_f32 %0, %1, %2" : "=v"(d1) : "v"(f1.x), "v"(f1.y));
  asm("v_cvt_pk_bf16_f32 %0, %1, %2" : "=v"(d2) : "v"(f2.x), "v"(f2.y));
  asm("v_cvt_pk_bf16_f32 %0, %1, %2" : "=v"(d3) : "v"(f3.x), "v"(f3.y));
  uint4 u = make_uint4(d0, d1, d2, d3);
  return __builtin_bit_cast(v8bf, u);
}

// ---------------- W (F x K*F f32) -> bf16 in MFMA-B-fragment order ----------
// Wt1 (standard): frag (k4=s*4+w4, c): lane holds W[c*16+l15, k4*32+lq*8+j].
// Wt2 (PERMUTED for fp8 PlanA): lane holds
//   W[c*16+l15, s*128 + (w4>>1)*64 + lq*16 + (w4&1)*8 + j]
// matching the A-side layout of 16B fp8 loads at row offset lq*16+i*64.
__global__ void wconv_kernel(const float* __restrict__ W1, const float* __restrict__ W2,
                             unsigned short* __restrict__ Wt1, unsigned short* __restrict__ Wt2) {
  int t = blockIdx.x * 256 + threadIdx.x;            // 65536 total
  const bool is2 = (t >= 32768);
  const float* W = is2 ? W2 : W1;
  unsigned short* Wt = is2 ? Wt2 : Wt1;
  int r = t & 32767;
  int frag = r >> 6, lane = r & 63;
  int k4 = frag >> 3, c = frag & 7;
  int o  = c * 16 + (lane & 15);
  int lq = lane >> 4;
  int kd;
  if (!is2) {
    kd = k4 * 32 + lq * 8;
  } else {
    int s_ = k4 >> 2, w_ = k4 & 3;
    kd = s_ * 128 + (w_ >> 1) * 64 + lq * 16 + (w_ & 1) * 8;
  }
  const float* src = W + o * 2048 + kd;
  unsigned short* dst = Wt + r * 8;
#pragma unroll
  for (int j = 0; j < 8; ++j) dst[j] = f2bf(src[j]);
}

// ---------------- BN stats over x (f32), deterministic two-phase ------------
__global__ void bn_stats_kernel(const float* __restrict__ x, float* __restrict__ part) {
  float s0=0,s1=0,s2=0,s3=0,q0=0,q1=0,q2=0,q3=0;
  for (int cb = blockIdx.x; cb < (NN*128/1024); cb += 256) {
    float4 v = reinterpret_cast<const float4*>(x)[cb * 256 + threadIdx.x];
    s0+=v.x; q0+=v.x*v.x; s1+=v.y; q1+=v.y*v.y;
    s2+=v.z; q2+=v.z*v.z; s3+=v.w; q3+=v.w*v.w;
  }
  __shared__ float ls[1024], lsq[1024];
  int fb = (threadIdx.x & 31) * 4;
  int sl = threadIdx.x >> 5;
  ls[sl*128+fb]   = s0; ls[sl*128+fb+1]  = s1; ls[sl*128+fb+2]  = s2; ls[sl*128+fb+3]  = s3;
  lsq[sl*128+fb]  = q0; lsq[sl*128+fb+1] = q1; lsq[sl*128+fb+2] = q2; lsq[sl*128+fb+3] = q3;
  __syncthreads();
  if (threadIdx.x < 128) {
    float S=0,Q=0;
#pragma unroll
    for (int s2i=0; s2i<8; ++s2i){ S += ls[s2i*128+threadIdx.x]; Q += lsq[s2i*128+threadIdx.x]; }
    part[blockIdx.x*256 + threadIdx.x]       = S;
    part[blockIdx.x*256 + 128 + threadIdx.x] = Q;
  }
}

// ---------------- final reduce: 1 block x 1024 thr, 8 groups x 128 feats ----
__global__ __launch_bounds__(1024) void bn_reduce_kernel(
    const float* __restrict__ part, int nb,
    const float* __restrict__ gamma, const float* __restrict__ beta,
    float* __restrict__ scsh) {
  int f = threadIdx.x & 127;
  int g = threadIdx.x >> 7;
  float S = 0.f, Q = 0.f;
  for (int b = g; b < nb; b += 8) {
    S += part[b * 256 + f];
    Q += part[b * 256 + 128 + f];
  }
  __shared__ float ls[8][128], lq[8][128];
  ls[g][f] = S; lq[g][f] = Q;
  __syncthreads();
  if (threadIdx.x < 128) {
    float St = 0.f, Qt = 0.f;
#pragma unroll
    for (int i = 0; i < 8; ++i) { St += ls[i][f]; Qt += lq[i][f]; }
    float inv  = 1.0f / (float)NN;
    float mean = St * inv;
    float var  = fmaxf(Qt * inv - mean * mean, 0.0f);
    float sc   = gamma[f] * rsqrtf(var + 1e-5f);
    scsh[f]       = sc;
    scsh[128 + f] = beta[f] - mean * sc;
  }
}

// ---------------- apply BN + GELU (exact erf), f32 source -> bf16 -----------
__global__ void apply1_kernel(const float* __restrict__ x, const float* __restrict__ scsh,
                              unsigned short* __restrict__ h1) {
  int stride = gridDim.x * blockDim.x;
  for (int c = blockIdx.x * blockDim.x + threadIdx.x; c < NN*128/4; c += stride) {
    float4 v = reinterpret_cast<const float4*>(x)[c];
    int f = (c * 4) & 127;
    ushort4 o;
    o.x = f2bf(gelu_f(v.x * scsh[f]   + scsh[128+f]));
    o.y = f2bf(gelu_f(v.y * scsh[f+1] + scsh[128+f+1]));
    o.z = f2bf(gelu_f(v.z * scsh[f+2] + scsh[128+f+2]));
    o.w = f2bf(gelu_f(v.w * scsh[f+3] + scsh[128+f+3]));
    reinterpret_cast<ushort4*>(h1)[c] = o;
  }
}

// ---------------- apply BN + GELU, bf16 source -> fp8 e4m3 ------------------
__global__ void apply2_kernel(const unsigned short* __restrict__ t1,
                              const float* __restrict__ scsh,
                              unsigned int* __restrict__ h2) {
  int stride = gridDim.x * blockDim.x;
  for (int c = blockIdx.x * blockDim.x + threadIdx.x; c < NN*128/8; c += stride) {
    u8s v = reinterpret_cast<const u8s*>(t1)[c];      // 8 bf16
    int f = (c * 8) & 127;
    float r[8];
#pragma unroll
    for (int j = 0; j < 8; ++j)
      r[j] = gelu_f(bf2f((unsigned short)v[j]) * scsh[f + j] + scsh[128 + f + j]);
    int lo = __builtin_amdgcn_cvt_pk_fp8_f32(r[0], r[1], 0,  false);
    lo     = __builtin_amdgcn_cvt_pk_fp8_f32(r[2], r[3], lo, true);
    int hi = __builtin_amdgcn_cvt_pk_fp8_f32(r[4], r[5], 0,  false);
    hi     = __builtin_amdgcn_cvt_pk_fp8_f32(r[6], r[7], hi, true);
    reinterpret_cast<uint2*>(h2)[c] = make_uint2((unsigned)lo, (unsigned)hi);
  }
}

// ---------------- RGCN ------------------------------------------------------
// Block = 4 waves, exactly 100 nodes (500 blocks). B: single 32KB LDS tile
// via global_load_lds, R8 SLOT schedule.
// MODE 0 (rgcn1): A = bf16 rows of h1 (8 gathers/slot/wave, instr floor);
//   epilogue = BN2 partials + LDS-transposed coalesced t1 store.
// MODE 1 (rgcn2): A = fp8 rows of h2, PLAN A: 4x dwordx4 (lane: 16B at row
//   offset lq*16+i*64); k-permutation folded into Wt2. Epilogue = +b2 +x.
template<int MODE>
__global__ __launch_bounds__(256, 2) void rgcn_kernel(
    const void* __restrict__ hb,
    const unsigned short* __restrict__ Wt,
    const int* __restrict__ graph,
    const float* __restrict__ bias,
    const float* __restrict__ xres,
    float* __restrict__ outf,
    unsigned short* __restrict__ outb,
    float* __restrict__ part)
{
  __shared__ unsigned short bsm[16384];      // 32KB: B tile, then t1 transpose
  __shared__ float lds_s[4][128];            // stats scratch (MODE 0)
  __shared__ float lds_q[4][128];

  const unsigned short* h16 = (const unsigned short*)hb;   // MODE 0
  const unsigned char*  h8  = (const unsigned char*)hb;    // MODE 1

  const int tid  = threadIdx.x;
  const int wv   = tid >> 6;
  const int lane = tid & 63;
  const int l15  = lane & 15;
  const int lq   = lane >> 4;
  const int nb0  = blockIdx.x * NPB;

  v4f acc[2][8];
#pragma unroll
  for (int rf = 0; rf < 2; ++rf)
#pragma unroll
    for (int c = 0; c < 8; ++c) acc[rf][c] = (v4f){0.f, 0.f, 0.f, 0.f};

  const int an0 = min(nb0 + wv * 32 + l15,      NN - 1);   // pad rows -> dup
  const int an1 = min(nb0 + wv * 32 + 16 + l15, NN - 1);

  // idx = row * 128 (elements; also bytes for fp8 since 1B/elem, rows 128B)
  int idx0[16], idx1[16];
  {
    const int4* g0 = reinterpret_cast<const int4*>(graph + an0 * 32);
    const int4* g1 = reinterpret_cast<const int4*>(graph + an1 * 32);
#pragma unroll
    for (int j = 0; j < 8; ++j) {
      int4 t0 = g0[j], t1v = g1[j];
      idx0[2*j]   = min(max(t0.y,  0), NN - 1) * 128;
      idx0[2*j+1] = min(max(t0.w,  0), NN - 1) * 128;
      idx1[2*j]   = min(max(t1v.y, 0), NN - 1) * 128;
      idx1[2*j+1] = min(max(t1v.w, 0), NN - 1) * 128;
    }
  }

  v8bf  A0[2][4],  A1[2][4];     // MODE 0 fragments (16B bf16)
  uint4 A0u[2][2], A1u[2][2];    // MODE 1: 16B fp8 chunks (2 per row)

#define LOADA(buf_, s_) {                                                 \
    if constexpr (MODE == 0) {                                            \
      const unsigned short* r0 = h16 + idx0[s_] + lq * 8;                 \
      const unsigned short* r1 = h16 + idx1[s_] + lq * 8;                 \
      _Pragma("unroll")                                                   \
      for (int w4 = 0; w4 < 4; ++w4) {                                    \
        A0[buf_][w4] = *reinterpret_cast<const v8bf*>(r0 + w4 * 32);      \
        A1[buf_][w4] = *reinterpret_cast<const v8bf*>(r1 + w4 * 32);      \
      }                                                                   \
    } else {                                                              \
      const unsigned char* r0 = h8 + idx0[s_] + lq * 16;                  \
      const unsigned char* r1 = h8 + idx1[s_] + lq * 16;                  \
      A0u[buf_][0] = *reinterpret_cast<const uint4*>(r0);                 \
      A0u[buf_][1] = *reinterpret_cast<const uint4*>(r0 + 64);            \
      A1u[buf_][0] = *reinterpret_cast<const uint4*>(r1);                 \
      A1u[buf_][1] = *reinterpret_cast<const uint4*>(r1 + 64);            \
    }                                                                     \
  }

#define STAGE(s_) {                                                           \
    const unsigned short* gsrc = Wt + (s_) * 16384 + wv * 4096 + lane * 8;    \
    unsigned short* ldst = &bsm[wv * 4096];                                   \
    _Pragma("unroll")                                                         \
    for (int i = 0; i < 8; ++i) {                                             \
      __builtin_amdgcn_global_load_lds(                                       \
        (const __attribute__((address_space(1))) void*)(gsrc + i * 512),      \
        (__attribute__((address_space(3))) void*)(ldst + i * 512),            \
        16, 0, 0);                                                            \
    }                                                                         \
  }

// index args masked so no OOB index appears textually (Sema array-bounds).
#define SLOT(s_) {                                                            \
    if ((s_) < 15) LOADA(((s_) + 1) & 1, ((s_) + 1) & 15)                     \
    __builtin_amdgcn_sched_barrier(0);                                        \
    __builtin_amdgcn_s_setprio(1);                                            \
    {                                                                         \
      const int cur_ = (s_) & 1;                                              \
      _Pragma("unroll")                                                       \
      for (int w4 = 0; w4 < 4; ++w4) {                                        \
        v8bf a0v, a1v;                                                        \
        if constexpr (MODE == 0) {                                            \
          a0v = A0[cur_][w4];                                                 \
          a1v = A1[cur_][w4];                                                 \
        } else {                                                              \
          uint4 u0 = A0u[cur_][w4 >> 1];                                      \
          uint4 u1 = A1u[cur_][w4 >> 1];                                      \
          if ((w4 & 1) == 0) {                                                \
            a0v = fp8x8_to_bf16x8(u0.x, u0.y);                                \
            a1v = fp8x8_to_bf16x8(u1.x, u1.y);                                \
          } else {                                                            \
            a0v = fp8x8_to_bf16x8(u0.z, u0.w);                                \
            a1v = fp8x8_to_bf16x8(u1.z, u1.w);                                \
          }                                                                   \
        }                                                                     \
        _Pragma("unroll")                                                     \
        for (int c = 0; c < 8; ++c) {                                         \
          v8bf b = *reinterpret_cast<const v8bf*>(                            \
              &bsm[(w4 * 8 + c) * 512 + lane * 8]);                           \
          acc[0][c] = __builtin_amdgcn_mfma_f32_16x16x32_bf16(                \
                        a0v, b, acc[0][c], 0, 0, 0);                          \
          acc[1][c] = __builtin_amdgcn_mfma_f32_16x16x32_bf16(                \
                        a1v, b, acc[1][c], 0, 0, 0);                          \
        }                                                                     \
      }                                                                       \
    }                                                                         \
    __builtin_amdgcn_s_setprio(0);                                            \
    __builtin_amdgcn_sched_barrier(0);                                        \
    __builtin_amdgcn_s_barrier();   /* all waves done reading bsm */          \
    __builtin_amdgcn_sched_barrier(0);                                        \
    if ((s_) < 15) STAGE(((s_) + 1) & 15)                                     \
    __syncthreads();                /* stage visible; gathers drained */      \
  }

  STAGE(0)
  LOADA(0, 0)
  __syncthreads();

  SLOT(0)  SLOT(1)  SLOT(2)  SLOT(3)
  SLOT(4)  SLOT(5)  SLOT(6)  SLOT(7)
  SLOT(8)  SLOT(9)  SLOT(10) SLOT(11)
  SLOT(12) SLOT(13) SLOT(14) SLOT(15)
#undef SLOT
#undef LOADA
#undef STAGE

  if constexpr (MODE == 0) {
    // BN2 partials (guarded to 100 valid rows) + bf16 into bsm tile,
    // then coalesced 16B/lane copy-out.
#pragma unroll
    for (int c = 0; c < 8; ++c) {
      float s = 0.f, q = 0.f;
#pragma unroll
      for (int rf = 0; rf < 2; ++rf) {
#pragma unroll
        for (int j = 0; j < 4; ++j) {
          int lrow = wv * 32 + rf * 16 + lq * 4 + j;    // C/D: row=(lane>>4)*4+reg
          float v  = acc[rf][c][j];
          if (lrow < NPB) { s += v; q += v * v; }
          bsm[lrow * 128 + c * 16 + l15] = f2bf(v);     // col = lane&15
        }
      }
      s += __shfl_xor(s, 16, 64); s += __shfl_xor(s, 32, 64);
      q += __shfl_xor(q, 16, 64); q += __shfl_xor(q, 32, 64);
      if (lq == 0) { lds_s[wv][c * 16 + l15] = s; lds_q[wv][c * 16 + l15] = q; }
    }
    __syncthreads();
    unsigned short* t1b = outb + nb0 * 128;
#pragma unroll
    for (int i = 0; i < 7; ++i) {
      int off = i * 2048 + tid * 8;                     // u16 units
      if (off < NPB * 128) {
        *reinterpret_cast<u8s*>(t1b + off) =
            *reinterpret_cast<const u8s*>(&bsm[off]);
      }
    }
    if (tid < 128) {
      float S = lds_s[0][tid] + lds_s[1][tid] + lds_s[2][tid] + lds_s[3][tid];
      float Q = lds_q[0][tid] + lds_q[1][tid] + lds_q[2][tid] + lds_q[3][tid];
      part[blockIdx.x * 256 + tid]       = S;
      part[blockIdx.x * 256 + 128 + tid] = Q;
    }
  } else {
#pragma unroll
    for (int c = 0; c < 8; ++c) {
      float bv = bias[c * 16 + l15];
#pragma unroll
      for (int rf = 0; rf < 2; ++rf) {
#pragma unroll
        for (int j = 0; j < 4; ++j) {
          int node = nb0 + wv * 32 + rf * 16 + lq * 4 + j;
          if (node < nb0 + NPB) {
            int idx = node * 128 + c * 16 + l15;
            outf[idx] = acc[rf][c][j] + bv + xres[idx];
          }
        }
      }
    }
  }
}

extern "C" void kernel_launch(void* const* d_in, const int* in_sizes, int n_in,
                              void* d_out, int out_size, void* d_ws, size_t ws_size,
                              hipStream_t stream) {
  const float* x      = (const float*)d_in[0];
  const int*   graph  = (const int*)d_in[1];
  const float* gamma1 = (const float*)d_in[2];
  const float* beta1  = (const float*)d_in[3];
  const float* W1     = (const float*)d_in[4];
  // d_in[5] = b1 : cancels inside BN2 (per-feature shift), skipped
  const float* gamma2 = (const float*)d_in[6];
  const float* beta2  = (const float*)d_in[7];
  const float* W2     = (const float*)d_in[8];
  const float* b2     = (const float*)d_in[9];
  float* out = (float*)d_out;

  char* ws = (char*)d_ws;
  // ws: h1(bf16)/h2(fp8) 12.8M | t1 12.8M | Wt1 512K | Wt2 512K | p1 | p2 | scsh
  unsigned short* h1  = (unsigned short*)(ws);
  unsigned short* t1  = (unsigned short*)(ws + 12800000);
  unsigned short* Wt1 = (unsigned short*)(ws + 25600000);
  unsigned short* Wt2 = (unsigned short*)(ws + 26124288);
  float* p1    = (float*)(ws + 26648576);
  float* p2    = (float*)(ws + 26910720);
  float* scsh1 = (float*)(ws + 27422720);
  float* scsh2 = (float*)(ws + 27423744);

  wconv_kernel<<<256, 256, 0, stream>>>(W1, W2, Wt1, Wt2);
  bn_stats_kernel<<<256, 256, 0, stream>>>(x, p1);
  bn_reduce_kernel<<<1, 1024, 0, stream>>>(p1, 256, gamma1, beta1, scsh1);
  apply1_kernel<<<2048, 256, 0, stream>>>(x, scsh1, h1);
  // args: (hb, Wt, graph, bias, xres, outf, outb, part)
  rgcn_kernel<0><<<NB, 256, 0, stream>>>(h1, Wt1, graph, nullptr, nullptr,
                                         nullptr, t1, p2);
  bn_reduce_kernel<<<1, 1024, 0, stream>>>(p2, NB, gamma2, beta2, scsh2);
  apply2_kernel<<<2048, 256, 0, stream>>>(t1, scsh2, (unsigned int*)h1);  // h2 (fp8) reuses h1
  rgcn_kernel<1><<<NB, 256, 0, stream>>>(h1, Wt2, graph, b2, x,
                                         out, nullptr, nullptr);
}